// Round 5
// baseline (848.036 us; speedup 1.0000x reference)
//
#include <hip/hip_runtime.h>
#include <cstdint>

#define EPSF 1e-5f

typedef __attribute__((ext_vector_type(8))) short short8;
typedef __attribute__((ext_vector_type(4))) float f32x4;
typedef __attribute__((ext_vector_type(4))) unsigned int u32x4;

// RNE float -> bf16 bits (inputs always finite here)
__device__ inline uint32_t bf16rne(float x) {
    uint32_t u = __builtin_bit_cast(uint32_t, x);
    return (u + 0x7fffu + ((u >> 16) & 1u)) >> 16;
}
__device__ inline float bf16f(uint32_t b) {
    return __builtin_bit_cast(float, b << 16);
}

// ============================== prep ==============================
// id ranges:
//  [0,288)          w2bits [co][tap] bit=ci
//  [288,21024)      wfcb POS-MAJOR [pos][j] bit=c, id ordered j-major for
//                   coalesced READS of wfc
//  [21024,21600)    BN3 (iv, sh) padded to 576
//  [21600,27360)    wlt [k][j] pad576
//  [27360,28128)    convA B-fragments in final per-lane layout
//  [28128,28160)    BN1 folded (iv, off=b0*iv+sh) as float2[32]
__global__ __launch_bounds__(256) void prep_kernel(
    const float* __restrict__ w2, const float* __restrict__ wfc,
    const float* __restrict__ g3, const float* __restrict__ be3,
    const float* __restrict__ m3, const float* __restrict__ v3,
    const float* __restrict__ wlast,
    const float* __restrict__ w0, const float* __restrict__ b0,
    const float* __restrict__ g1, const float* __restrict__ be1,
    const float* __restrict__ m1, const float* __restrict__ v1,
    uint32_t* __restrict__ w2bits, uint32_t* __restrict__ wfcb,
    float* __restrict__ inv3p, float* __restrict__ sh3p, float* __restrict__ wlt,
    uint32_t* __restrict__ bfrag, float2* __restrict__ bn1c)
{
    int id = blockIdx.x * 256 + threadIdx.x;
    if (id < 288) {
        int co = id / 9, r = id % 9;
        uint32_t b = 0;
        for (int ci = 0; ci < 32; ci++)
            b |= (uint32_t)(w2[(co * 32 + ci) * 9 + r] < 0.f) << ci;
        w2bits[id] = b;
        return;
    }
    id -= 288;
    if (id < 36 * 576) {                  // j-major iteration, pos-major storage
        int j = id / 36, pos = id % 36;
        uint32_t b = 0;
        if (j < 516) {
            const float* row = wfc + j * 1152 + pos;
            for (int c = 0; c < 32; c++)
                b |= (uint32_t)(row[c * 36] < 0.f) << c;
        }
        wfcb[pos * 576 + j] = b;
        return;
    }
    id -= 36 * 576;
    if (id < 576) {
        float iv = 0.f, sh = 0.f;
        if (id < 516) {
            iv = g3[id] / sqrtf(__fadd_rn(v3[id], EPSF));
            sh = __fsub_rn(be3[id], __fmul_rn(m3[id], iv));
        }
        inv3p[id] = iv; sh3p[id] = sh;
        return;
    }
    id -= 576;
    if (id < 5760) {
        int k = id / 576, j = id % 576;
        wlt[id] = (j < 516) ? wlast[k * 516 + j] : 0.f;
        return;
    }
    id -= 5760;
    if (id < 768) {                       // B fragments
        int L = id / 12, r = id % 12;
        int nt = r / 6, s = (r % 6) / 2, h = r & 1;
        int g = L >> 4, n = L & 15;
        int tap = 4 * s + g;
        uint32_t d[4] = {0, 0, 0, 0};
        if (tap < 9) {
            int co = nt * 16 + n;
            for (int j2 = 0; j2 < 4; j2++) {
                float wa = w0[co * 72 + (2 * j2) * 9 + tap];
                float wb = w0[co * 72 + (2 * j2 + 1) * 9 + tap];
                uint32_t ha = bf16rne(wa), hb = bf16rne(wb);
                uint32_t va, vb;
                if (h == 0) { va = ha; vb = hb; }
                else { va = bf16rne(wa - bf16f(ha)); vb = bf16rne(wb - bf16f(hb)); }
                d[j2] = va | (vb << 16);
            }
        }
        *(u32x4*)(bfrag + id * 4) = (u32x4){d[0], d[1], d[2], d[3]};
        return;
    }
    id -= 768;
    if (id < 32) {                        // BN1 folded constants
        float iv = g1[id] / sqrtf(__fadd_rn(v1[id], EPSF));
        float sh = __fsub_rn(be1[id], __fmul_rn(m1[id], iv));
        float off = __fadd_rn(__fmul_rn(b0[id], iv), sh);
        bn1c[id] = make_float2(iv, off);
    }
}

// ================== conv1 fp64 sign recheck (rare) ==================
// 4 interleaved fp64 chains instead of one 72-deep serial chain:
// dependent-FMA latency path ~72 -> ~18 deep. fp64 reassociation error
// (~2^-50) is irrelevant vs the 3e-4 trigger threshold.
__device__ __noinline__ bool recheck_sign(const float* __restrict__ xim,
                                          const float* __restrict__ w0,
                                          int py, int px, int co,
                                          float ivc, float offc)
{
    double ad0 = 0.0, ad1 = 0.0, ad2 = 0.0, ad3 = 0.0;
    #pragma unroll
    for (int ci = 0; ci < 8; ci++) {
        #pragma unroll
        for (int ky = 0; ky < 3; ky++) {
            #pragma unroll
            for (int kx = 0; kx < 3; kx++) {
                int k = ci * 9 + ky * 3 + kx;
                double p = (double)xim[ci * 256 + (py + ky) * 16 + px + kx];
                double w = (double)w0[co * 72 + ci * 9 + ky * 3 + kx];
                if ((k & 3) == 0)      ad0 = fma(p, w, ad0);
                else if ((k & 3) == 1) ad1 = fma(p, w, ad1);
                else if ((k & 3) == 2) ad2 = fma(p, w, ad2);
                else                   ad3 = fma(p, w, ad3);
            }
        }
    }
    double ad = (ad0 + ad1) + (ad2 + ad3);
    return (ad * (double)ivc + (double)offc) < 0.0;
}

// ============================== convAB ==============================
// FUSED conv1(MFMA)+BN1+sign -> s1 bits in LDS -> binary conv2+BN2+
// hardtanh+maxpool+sign -> fcin (global).
// R5 CRITICAL-PATH CUT: residency experiments (R0/R2/R3/R4) proved the
// kernel is NOT residency-bound (active waves pinned ~11-12/CU at every
// static ceiling 16..32). So shorten per-wave dependency chains instead:
//  - 6 independent MFMA partial-accumulator chains (depth 3) instead of
//    2 chains of depth 9 (dep-MFMA latency ~16cy vs 5cy issue).
//  - recheck_sign: 4 interleaved fp64 chains (see above).
// Structure otherwise identical to R3 (best measured: 95us).
__global__ __launch_bounds__(128, 4) void convAB(
    const float* __restrict__ x, const float* __restrict__ w0,
    const uint32_t* __restrict__ bfrag, const float2* __restrict__ bn1c,
    const uint32_t* __restrict__ w2bits,
    const float* __restrict__ g2, const float* __restrict__ be2,
    const float* __restrict__ m2, const float* __restrict__ v2,
    uint32_t* __restrict__ fcin)
{
    __shared__ __align__(16) char simg[9216];
    __shared__ __align__(8) uint32_t s1l[196];

    const int t = threadIdx.x;
    const int wv = t >> 6, lane = t & 63;
    const int img = blockIdx.x;
    const float* xim = x + img * 2048;
    char* hib = simg;
    char* lob = simg + 4608;

    const int g = lane >> 4;              // quad
    const int n = lane & 15;

    // ---- B fragments: 12 x 16B per lane, precomputed in prep
    short8 Bh[2][3], Bl[2][3];
    {
        const uint32_t* bb = bfrag + lane * 48;
        #pragma unroll
        for (int nt = 0; nt < 2; nt++)
            #pragma unroll
            for (int s = 0; s < 3; s++) {
                Bh[nt][s] = *(const short8*)(bb + (nt * 6 + s * 2) * 4);
                Bl[nt][s] = *(const short8*)(bb + (nt * 6 + s * 2 + 1) * 4);
            }
    }
    const float2 bnA = bn1c[n], bnB = bn1c[16 + n];

    // ---- stage image cooperatively: wave wv handles pos-groups {2wv, 2wv+1}
    #pragma unroll
    for (int qq = 0; qq < 2; qq++) {
        int pos = lane + 64 * (2 * wv + qq);
        uint32_t hw[4], lw[4];
        #pragma unroll
        for (int j2 = 0; j2 < 4; j2++) {
            float a = xim[(2 * j2) * 256 + pos];
            float b = xim[(2 * j2 + 1) * 256 + pos];
            uint32_t ha = bf16rne(a), hb = bf16rne(b);
            uint32_t la = bf16rne(a - bf16f(ha)), lb = bf16rne(b - bf16f(hb));
            hw[j2] = ha | (hb << 16);
            lw[j2] = la | (lb << 16);
        }
        *(u32x4*)(hib + pos * 16) = (u32x4){hw[0], hw[1], hw[2], hw[3]};
        *(u32x4*)(lob + pos * 16) = (u32x4){lw[0], lw[1], lw[2], lw[3]};
    }
    if (lane < 32) {                      // zero guard slots 256..287 (split by wave)
        char* gp = (wv == 0) ? hib : lob;
        *(u32x4*)(gp + (256 + lane) * 16) = (u32x4){0, 0, 0, 0};
    }

    // per-lane A LDS byte offsets per K-step (tap window); pad-taps -> 0 (B=0)
    int koff[3];
    #pragma unroll
    for (int s = 0; s < 3; s++) {
        int tap = 4 * s + g;
        koff[s] = (tap < 9) ? ((tap / 3) * 16 + (tap % 3)) * 16 : 0;
    }

    __syncthreads();

    // ---- phase 2: MFMA tiles (split even/odd across waves), s1 -> LDS
    for (int tile = wv; tile < 13; tile += 2) {
        int posA = tile * 16 + n;
        int pyA = posA / 14, pxA = posA - pyA * 14;
        int sl = (pyA * 16 + pxA) * 16;

        // 6 independent partial-accumulator chains (depth 3 each):
        // p{0,1}{a,b,c}: a=Al*Bh, b=Ah*Bl, c=Ah*Bh per output-co half.
        f32x4 p0a = {0.f, 0.f, 0.f, 0.f}, p0b = p0a, p0c = p0a;
        f32x4 p1a = p0a, p1b = p0a, p1c = p0a;
        __builtin_amdgcn_s_setprio(1);
        #pragma unroll
        for (int s = 0; s < 3; s++) {
            short8 Ah = *(const short8*)(hib + sl + koff[s]);
            short8 Al = *(const short8*)(lob + sl + koff[s]);
            p0a = __builtin_amdgcn_mfma_f32_16x16x32_bf16(Al, Bh[0][s], p0a, 0, 0, 0);
            p0b = __builtin_amdgcn_mfma_f32_16x16x32_bf16(Ah, Bl[0][s], p0b, 0, 0, 0);
            p0c = __builtin_amdgcn_mfma_f32_16x16x32_bf16(Ah, Bh[0][s], p0c, 0, 0, 0);
            p1a = __builtin_amdgcn_mfma_f32_16x16x32_bf16(Al, Bh[1][s], p1a, 0, 0, 0);
            p1b = __builtin_amdgcn_mfma_f32_16x16x32_bf16(Ah, Bl[1][s], p1b, 0, 0, 0);
            p1c = __builtin_amdgcn_mfma_f32_16x16x32_bf16(Ah, Bh[1][s], p1c, 0, 0, 0);
        }
        __builtin_amdgcn_s_setprio(0);
        f32x4 acc0 = (p0a + p0b) + p0c;
        f32x4 acc1 = (p1a + p1b) + p1c;

        // epilogue: C/D row = 4*g + r (pos), col = n (co / co+16)
        #pragma unroll
        for (int r = 0; r < 4; r++) {
            int pos = tile * 16 + 4 * g + r;
            float yv0 = fmaf(acc0[r], bnA.x, bnA.y);
            float yv1 = fmaf(acc1[r], bnB.x, bnB.y);
            bool bit0, bit1;
            if (__builtin_expect(pos < 196 && fabsf(yv0) < 3e-4f, 0)) {
                int py = pos / 14, px = pos - py * 14;
                bit0 = recheck_sign(xim, w0, py, px, n, bnA.x, bnA.y);
            } else bit0 = (yv0 < 0.f);
            if (__builtin_expect(pos < 196 && fabsf(yv1) < 3e-4f, 0)) {
                int py = pos / 14, px = pos - py * 14;
                bit1 = recheck_sign(xim, w0, py, px, 16 + n, bnB.x, bnB.y);
            } else bit1 = (yv1 < 0.f);
            unsigned long long m0 = __ballot(bit0);
            unsigned long long m1 = __ballot(bit1);
            uint32_t word = (uint32_t)((m0 >> (16 * g)) & 0xffffull)
                          | ((uint32_t)((m1 >> (16 * g)) & 0xffffull) << 16);
            if (n == 0 && pos < 196) s1l[pos] = word;
        }
    }

    __syncthreads();
    __builtin_amdgcn_sched_barrier(0);    // keep phase-4 loads out of phase-2 RA peak

    // ---- phase 4: binary conv2 + BN2 + maxpool + sign, from LDS s1l.
    // wave wv -> y2 in {3wv..3wv+2}; half-wave h -> x2 = step + 3h; c = lane&31.
    {
        const int c = lane & 31, h = lane >> 5;
        uint32_t wr[9];
        #pragma unroll
        for (int k = 0; k < 9; k++) wr[k] = w2bits[c * 9 + k];
        float ivv = g2[c] / sqrtf(__fadd_rn(v2[c], EPSF));
        float shv = __fsub_rn(be2[c], __fmul_rn(m2[c], ivv));
        uint32_t* outp = fcin + img * 36;
        const int cb0 = 6 * h;            // column base for this half-wave

        for (int yy = 0; yy < 3; yy++) {
            const int y2 = 3 * wv + yy;
            const int rbase = 2 * y2 * 14;
            uint32_t win[4][4];
            #pragma unroll
            for (int rr = 0; rr < 4; rr++) {
                uint2 a = *(const uint2*)&s1l[rbase + rr * 14 + cb0];
                uint2 b = *(const uint2*)&s1l[rbase + rr * 14 + cb0 + 2];
                win[rr][0] = a.x; win[rr][1] = a.y; win[rr][2] = b.x; win[rr][3] = b.y;
            }
            for (int step = 0; step < 3; step++) {
                if (step > 0) {
                    #pragma unroll
                    for (int rr = 0; rr < 4; rr++) {
                        win[rr][0] = win[rr][2]; win[rr][1] = win[rr][3];
                        uint2 b = *(const uint2*)&s1l[rbase + rr * 14 + cb0 + 2 * step + 2];
                        win[rr][2] = b.x; win[rr][3] = b.y;
                    }
                }
                int mx = -10000;
                #pragma unroll
                for (int dy = 0; dy < 2; dy++)
                    #pragma unroll
                    for (int dx = 0; dx < 2; dx++) {
                        int p = 0;
                        #pragma unroll
                        for (int ky = 0; ky < 3; ky++)
                            #pragma unroll
                            for (int kx = 0; kx < 3; kx++)
                                p += __popc(win[dy + ky][dx + kx] ^ wr[ky * 3 + kx]);
                        mx = max(mx, 288 - 2 * p);
                    }
                float yv = __fadd_rn(__fmul_rn((float)mx, ivv), shv);
                unsigned long long mb = __ballot(yv < 0.f);
                if (lane == 0)  outp[y2 * 6 + step]     = (uint32_t)mb;
                if (lane == 32) outp[y2 * 6 + step + 3] = (uint32_t)(mb >> 32);
            }
        }
    }
}

// ============================== fcC ==============================
// binary FC + BN3 + hardtanh + final 516x10 linear. wave = 2 batches.
__global__ __launch_bounds__(256) void fcC(
    const uint32_t* __restrict__ fcin, const uint32_t* __restrict__ wfcb,
    const float* __restrict__ inv3p, const float* __restrict__ sh3p,
    const float* __restrict__ wlt, const float* __restrict__ blast,
    float* __restrict__ out)
{
    __shared__ uint32_t l_in[288];
    const int t = threadIdx.x, wid = t >> 6, lane = t & 63;

    for (int i = t; i < 288; i += 256) l_in[i] = fcin[blockIdx.x * 288 + i];
    __syncthreads();

    const int b0i = blockIdx.x * 8 + wid * 2;
    const uint32_t* in0 = &l_in[wid * 72];

    int pc0[9], pc1[9];
    #pragma unroll
    for (int q = 0; q < 9; q++) { pc0[q] = 0; pc1[q] = 0; }

    for (int w = 0; w < 36; w++) {
        uint32_t i0 = in0[w], i1 = in0[36 + w];
        const uint32_t* wf = wfcb + w * 576 + lane;
        #pragma unroll
        for (int q = 0; q < 9; q++) {
            uint32_t f = wf[q * 64];
            pc0[q] += __popc(i0 ^ f);
            pc1[q] += __popc(i1 ^ f);
        }
    }

    float oa[2][10];
    #pragma unroll
    for (int b = 0; b < 2; b++)
        #pragma unroll
        for (int k = 0; k < 10; k++) oa[b][k] = 0.f;

    #pragma unroll
    for (int q = 0; q < 9; q++) {
        int j = lane + 64 * q;
        float ivv = inv3p[j], shv = sh3p[j];
        float t0 = fminf(1.f, fmaxf(-1.f, __fadd_rn(__fmul_rn((float)(1152 - 2 * pc0[q]), ivv), shv)));
        float t1 = fminf(1.f, fmaxf(-1.f, __fadd_rn(__fmul_rn((float)(1152 - 2 * pc1[q]), ivv), shv)));
        #pragma unroll
        for (int k = 0; k < 10; k++) {
            float wv = wlt[k * 576 + j];
            oa[0][k] = fmaf(t0, wv, oa[0][k]);
            oa[1][k] = fmaf(t1, wv, oa[1][k]);
        }
    }

    #pragma unroll
    for (int m = 1; m < 64; m <<= 1)
        #pragma unroll
        for (int b = 0; b < 2; b++)
            #pragma unroll
            for (int k = 0; k < 10; k++)
                oa[b][k] += __shfl_xor(oa[b][k], m, 64);

    if (lane == 0) {
        for (int b = 0; b < 2; b++)
            for (int k = 0; k < 10; k++)
                out[(b0i + b) * 10 + k] = oa[b][k] + blast[k];
    }
}

// ============================== launch ==============================
extern "C" void kernel_launch(void* const* d_in, const int* in_sizes, int n_in,
                              void* d_out, int out_size, void* d_ws, size_t ws_size,
                              hipStream_t stream)
{
    (void)in_sizes; (void)n_in; (void)out_size; (void)ws_size;
    const float* x     = (const float*)d_in[0];
    const float* w0    = (const float*)d_in[1];
    const float* b0    = (const float*)d_in[2];
    const float* g1    = (const float*)d_in[3];
    const float* be1   = (const float*)d_in[4];
    const float* m1    = (const float*)d_in[5];
    const float* v1    = (const float*)d_in[6];
    const float* w2    = (const float*)d_in[7];
    const float* g2    = (const float*)d_in[8];
    const float* be2   = (const float*)d_in[9];
    const float* m2    = (const float*)d_in[10];
    const float* v2    = (const float*)d_in[11];
    const float* wfc   = (const float*)d_in[12];
    const float* g3    = (const float*)d_in[13];
    const float* be3   = (const float*)d_in[14];
    const float* m3    = (const float*)d_in[15];
    const float* v3    = (const float*)d_in[16];
    const float* wlast = (const float*)d_in[17];
    const float* blast = (const float*)d_in[18];

    char* ws = (char*)d_ws;
    uint32_t* fcin   = (uint32_t*)(ws + 6422528);       // 8192*36*4  = 1,179,648 B
    uint32_t* w2bits = (uint32_t*)(ws + 7602176);       // 288*4
    uint32_t* wfcb   = (uint32_t*)(ws + 7603328);       // 36*576*4 = 82,944 B
    float*    inv3p  = (float*)(ws + 7686272);          // 576*4
    float*    sh3p   = (float*)(ws + 7688576);          // 576*4
    float*    wlt    = (float*)(ws + 7690880);          // 10*576*4 = 23,040 B
    uint32_t* bfrag  = (uint32_t*)(ws + 7713920);       // 768*16 = 12,288 B (16B aligned)
    float2*   bn1c   = (float2*)(ws + 7726208);         // 32*8 = 256 B

    prep_kernel<<<110, 256, 0, stream>>>(w2, wfc, g3, be3, m3, v3, wlast,
                                         w0, b0, g1, be1, m1, v1,
                                         w2bits, wfcb, inv3p, sh3p, wlt,
                                         bfrag, bn1c);
    convAB<<<8192, 128, 0, stream>>>(x, w0, bfrag, bn1c,
                                     w2bits, g2, be2, m2, v2, fcin);
    fcC<<<1024, 256, 0, stream>>>(fcin, wfcb, inv3p, sh3p, wlt, blast, (float*)d_out);
}

// Round 8
// 214.987 us; speedup vs baseline: 3.9446x; 3.9446x over previous
//
#include <hip/hip_runtime.h>
#include <cstdint>

#define EPSF 1e-5f

typedef __attribute__((ext_vector_type(8))) short short8;
typedef __attribute__((ext_vector_type(4))) float f32x4;
typedef __attribute__((ext_vector_type(4))) unsigned int u32x4;

// RNE float -> bf16 bits (inputs always finite here)
__device__ inline uint32_t bf16rne(float x) {
    uint32_t u = __builtin_bit_cast(uint32_t, x);
    return (u + 0x7fffu + ((u >> 16) & 1u)) >> 16;
}
__device__ inline float bf16f(uint32_t b) {
    return __builtin_bit_cast(float, b << 16);
}

// ============================== prep ==============================
// id ranges:
//  [0,288)          w2bits [co][tap] bit=ci
//  [288,21024)      wfcb POS-MAJOR [pos][j] bit=c
//  [21024,21600)    BN3 (iv, sh) padded to 576
//  [21600,27360)    wlt [k][j] pad576
//  [27360,28128)    convA B-fragments in final per-lane layout
//  [28128,28160)    BN1 folded (iv, off=b0*iv+sh) as float2[32]
__global__ __launch_bounds__(256) void prep_kernel(
    const float* __restrict__ w2, const float* __restrict__ wfc,
    const float* __restrict__ g3, const float* __restrict__ be3,
    const float* __restrict__ m3, const float* __restrict__ v3,
    const float* __restrict__ wlast,
    const float* __restrict__ w0, const float* __restrict__ b0,
    const float* __restrict__ g1, const float* __restrict__ be1,
    const float* __restrict__ m1, const float* __restrict__ v1,
    uint32_t* __restrict__ w2bits, uint32_t* __restrict__ wfcb,
    float* __restrict__ inv3p, float* __restrict__ sh3p, float* __restrict__ wlt,
    uint32_t* __restrict__ bfrag, float2* __restrict__ bn1c)
{
    int id = blockIdx.x * 256 + threadIdx.x;
    if (id < 288) {
        int co = id / 9, r = id % 9;
        uint32_t b = 0;
        for (int ci = 0; ci < 32; ci++)
            b |= (uint32_t)(w2[(co * 32 + ci) * 9 + r] < 0.f) << ci;
        w2bits[id] = b;
        return;
    }
    id -= 288;
    if (id < 36 * 576) {                  // j-major iteration, pos-major storage
        int j = id / 36, pos = id % 36;
        uint32_t b = 0;
        if (j < 516) {
            const float* row = wfc + j * 1152 + pos;
            for (int c = 0; c < 32; c++)
                b |= (uint32_t)(row[c * 36] < 0.f) << c;
        }
        wfcb[pos * 576 + j] = b;
        return;
    }
    id -= 36 * 576;
    if (id < 576) {
        float iv = 0.f, sh = 0.f;
        if (id < 516) {
            iv = g3[id] / sqrtf(__fadd_rn(v3[id], EPSF));
            sh = __fsub_rn(be3[id], __fmul_rn(m3[id], iv));
        }
        inv3p[id] = iv; sh3p[id] = sh;
        return;
    }
    id -= 576;
    if (id < 5760) {
        int k = id / 576, j = id % 576;
        wlt[id] = (j < 516) ? wlast[k * 516 + j] : 0.f;
        return;
    }
    id -= 5760;
    if (id < 768) {                       // B fragments
        int L = id / 12, r = id % 12;
        int nt = r / 6, s = (r % 6) / 2, h = r & 1;
        int g = L >> 4, n = L & 15;
        int tap = 4 * s + g;
        uint32_t d[4] = {0, 0, 0, 0};
        if (tap < 9) {
            int co = nt * 16 + n;
            for (int j2 = 0; j2 < 4; j2++) {
                float wa = w0[co * 72 + (2 * j2) * 9 + tap];
                float wb = w0[co * 72 + (2 * j2 + 1) * 9 + tap];
                uint32_t ha = bf16rne(wa), hb = bf16rne(wb);
                uint32_t va, vb;
                if (h == 0) { va = ha; vb = hb; }
                else { va = bf16rne(wa - bf16f(ha)); vb = bf16rne(wb - bf16f(hb)); }
                d[j2] = va | (vb << 16);
            }
        }
        *(u32x4*)(bfrag + id * 4) = (u32x4){d[0], d[1], d[2], d[3]};
        return;
    }
    id -= 768;
    if (id < 32) {                        // BN1 folded constants
        float iv = g1[id] / sqrtf(__fadd_rn(v1[id], EPSF));
        float sh = __fsub_rn(be1[id], __fmul_rn(m1[id], iv));
        float off = __fadd_rn(__fmul_rn(b0[id], iv), sh);
        bn1c[id] = make_float2(iv, off);
    }
}

// ================== conv1 fp64 sign recheck (rare) ==================
__device__ __noinline__ bool recheck_sign(const float* __restrict__ xim,
                                          const float* __restrict__ w0,
                                          int py, int px, int co,
                                          float ivc, float offc)
{
    double ad = 0.0;
    for (int ci = 0; ci < 8; ci++)
        for (int ky = 0; ky < 3; ky++)
            for (int kx = 0; kx < 3; kx++)
                ad = fma((double)xim[ci * 256 + (py + ky) * 16 + px + kx],
                         (double)w0[co * 72 + ci * 9 + ky * 3 + kx], ad);
    return (ad * (double)ivc + (double)offc) < 0.0;
}

// ============================== convAB ==============================
// FUSED conv1(MFMA)+BN1+sign -> s1 bits in LDS -> binary conv2+BN2+
// hardtanh+maxpool+sign -> fcin (global). EXACT R3 structure (passed,
// convAB=95us) with the two scheduling grafts REMOVED for a clean A/B:
//  - s_setprio(1/0) around MFMA: T5 is null-to-negative in lockstep
//    barrier-synced structures (m190); this kernel is that regime.
//  - sched_barrier(0) after the phase boundary: full order-pinning is
//    the worst-measured graft (m141); it also blocked the compiler from
//    hoisting phase-4's independent w2bits/BN2 loads into phase-2's
//    stall shadow (__syncthreads already orders the only real dep, s1l).
// R1/R5 lesson stands: spill cliff at 64 arch VGPRs; do not add live
// registers to phase 2. NO cross-block atomics (R6/R7 container deaths
// correlate with the atomic-election kernel under rocprof replay).
__global__ __launch_bounds__(128, 4) void convAB(
    const float* __restrict__ x, const float* __restrict__ w0,
    const uint32_t* __restrict__ bfrag, const float2* __restrict__ bn1c,
    const uint32_t* __restrict__ w2bits,
    const float* __restrict__ g2, const float* __restrict__ be2,
    const float* __restrict__ m2, const float* __restrict__ v2,
    uint32_t* __restrict__ fcin)
{
    __shared__ __align__(16) char simg[9216];
    __shared__ __align__(8) uint32_t s1l[196];

    const int t = threadIdx.x;
    const int wv = t >> 6, lane = t & 63;
    const int img = blockIdx.x;
    const float* xim = x + img * 2048;
    char* hib = simg;
    char* lob = simg + 4608;

    const int g = lane >> 4;              // quad
    const int n = lane & 15;

    // ---- B fragments: 12 x 16B per lane, precomputed in prep
    short8 Bh[2][3], Bl[2][3];
    {
        const uint32_t* bb = bfrag + lane * 48;
        #pragma unroll
        for (int nt = 0; nt < 2; nt++)
            #pragma unroll
            for (int s = 0; s < 3; s++) {
                Bh[nt][s] = *(const short8*)(bb + (nt * 6 + s * 2) * 4);
                Bl[nt][s] = *(const short8*)(bb + (nt * 6 + s * 2 + 1) * 4);
            }
    }
    const float2 bnA = bn1c[n], bnB = bn1c[16 + n];

    // ---- stage image cooperatively: wave wv handles pos-groups {2wv, 2wv+1}
    #pragma unroll
    for (int qq = 0; qq < 2; qq++) {
        int pos = lane + 64 * (2 * wv + qq);
        uint32_t hw[4], lw[4];
        #pragma unroll
        for (int j2 = 0; j2 < 4; j2++) {
            float a = xim[(2 * j2) * 256 + pos];
            float b = xim[(2 * j2 + 1) * 256 + pos];
            uint32_t ha = bf16rne(a), hb = bf16rne(b);
            uint32_t la = bf16rne(a - bf16f(ha)), lb = bf16rne(b - bf16f(hb));
            hw[j2] = ha | (hb << 16);
            lw[j2] = la | (lb << 16);
        }
        *(u32x4*)(hib + pos * 16) = (u32x4){hw[0], hw[1], hw[2], hw[3]};
        *(u32x4*)(lob + pos * 16) = (u32x4){lw[0], lw[1], lw[2], lw[3]};
    }
    if (lane < 32) {                      // zero guard slots 256..287 (split by wave)
        char* gp = (wv == 0) ? hib : lob;
        *(u32x4*)(gp + (256 + lane) * 16) = (u32x4){0, 0, 0, 0};
    }

    // per-lane A LDS byte offsets per K-step (tap window); pad-taps -> 0 (B=0)
    int koff[3];
    #pragma unroll
    for (int s = 0; s < 3; s++) {
        int tap = 4 * s + g;
        koff[s] = (tap < 9) ? ((tap / 3) * 16 + (tap % 3)) * 16 : 0;
    }

    __syncthreads();

    // ---- phase 2: MFMA tiles (split even/odd across waves), s1 -> LDS
    for (int tile = wv; tile < 13; tile += 2) {
        int posA = tile * 16 + n;
        int pyA = posA / 14, pxA = posA - pyA * 14;
        int sl = (pyA * 16 + pxA) * 16;

        f32x4 acc0 = {0.f, 0.f, 0.f, 0.f}, acc1 = {0.f, 0.f, 0.f, 0.f};
        #pragma unroll
        for (int s = 0; s < 3; s++) {
            short8 Ah = *(const short8*)(hib + sl + koff[s]);
            short8 Al = *(const short8*)(lob + sl + koff[s]);
            acc0 = __builtin_amdgcn_mfma_f32_16x16x32_bf16(Al, Bh[0][s], acc0, 0, 0, 0);
            acc0 = __builtin_amdgcn_mfma_f32_16x16x32_bf16(Ah, Bl[0][s], acc0, 0, 0, 0);
            acc0 = __builtin_amdgcn_mfma_f32_16x16x32_bf16(Ah, Bh[0][s], acc0, 0, 0, 0);
            acc1 = __builtin_amdgcn_mfma_f32_16x16x32_bf16(Al, Bh[1][s], acc1, 0, 0, 0);
            acc1 = __builtin_amdgcn_mfma_f32_16x16x32_bf16(Ah, Bl[1][s], acc1, 0, 0, 0);
            acc1 = __builtin_amdgcn_mfma_f32_16x16x32_bf16(Ah, Bh[1][s], acc1, 0, 0, 0);
        }

        // epilogue: C/D row = 4*g + r (pos), col = n (co / co+16)
        #pragma unroll
        for (int r = 0; r < 4; r++) {
            int pos = tile * 16 + 4 * g + r;
            float yv0 = fmaf(acc0[r], bnA.x, bnA.y);
            float yv1 = fmaf(acc1[r], bnB.x, bnB.y);
            bool bit0, bit1;
            if (__builtin_expect(pos < 196 && fabsf(yv0) < 3e-4f, 0)) {
                int py = pos / 14, px = pos - py * 14;
                bit0 = recheck_sign(xim, w0, py, px, n, bnA.x, bnA.y);
            } else bit0 = (yv0 < 0.f);
            if (__builtin_expect(pos < 196 && fabsf(yv1) < 3e-4f, 0)) {
                int py = pos / 14, px = pos - py * 14;
                bit1 = recheck_sign(xim, w0, py, px, 16 + n, bnB.x, bnB.y);
            } else bit1 = (yv1 < 0.f);
            unsigned long long m0 = __ballot(bit0);
            unsigned long long m1 = __ballot(bit1);
            uint32_t word = (uint32_t)((m0 >> (16 * g)) & 0xffffull)
                          | ((uint32_t)((m1 >> (16 * g)) & 0xffffull) << 16);
            if (n == 0 && pos < 196) s1l[pos] = word;
        }
    }

    __syncthreads();

    // ---- phase 4: binary conv2 + BN2 + maxpool + sign, from LDS s1l.
    // wave wv -> y2 in {3wv..3wv+2}; half-wave h -> x2 = step + 3h; c = lane&31.
    {
        const int c = lane & 31, h = lane >> 5;
        uint32_t wr[9];
        #pragma unroll
        for (int k = 0; k < 9; k++) wr[k] = w2bits[c * 9 + k];
        float ivv = g2[c] / sqrtf(__fadd_rn(v2[c], EPSF));
        float shv = __fsub_rn(be2[c], __fmul_rn(m2[c], ivv));
        uint32_t* outp = fcin + img * 36;
        const int cb0 = 6 * h;            // column base for this half-wave

        for (int yy = 0; yy < 3; yy++) {
            const int y2 = 3 * wv + yy;
            const int rbase = 2 * y2 * 14;
            uint32_t win[4][4];
            #pragma unroll
            for (int rr = 0; rr < 4; rr++) {
                uint2 a = *(const uint2*)&s1l[rbase + rr * 14 + cb0];
                uint2 b = *(const uint2*)&s1l[rbase + rr * 14 + cb0 + 2];
                win[rr][0] = a.x; win[rr][1] = a.y; win[rr][2] = b.x; win[rr][3] = b.y;
            }
            for (int step = 0; step < 3; step++) {
                if (step > 0) {
                    #pragma unroll
                    for (int rr = 0; rr < 4; rr++) {
                        win[rr][0] = win[rr][2]; win[rr][1] = win[rr][3];
                        uint2 b = *(const uint2*)&s1l[rbase + rr * 14 + cb0 + 2 * step + 2];
                        win[rr][2] = b.x; win[rr][3] = b.y;
                    }
                }
                int mx = -10000;
                #pragma unroll
                for (int dy = 0; dy < 2; dy++)
                    #pragma unroll
                    for (int dx = 0; dx < 2; dx++) {
                        int p = 0;
                        #pragma unroll
                        for (int ky = 0; ky < 3; ky++)
                            #pragma unroll
                            for (int kx = 0; kx < 3; kx++)
                                p += __popc(win[dy + ky][dx + kx] ^ wr[ky * 3 + kx]);
                        mx = max(mx, 288 - 2 * p);
                    }
                float yv = __fadd_rn(__fmul_rn((float)mx, ivv), shv);
                unsigned long long mb = __ballot(yv < 0.f);
                if (lane == 0)  outp[y2 * 6 + step]     = (uint32_t)mb;
                if (lane == 32) outp[y2 * 6 + step + 3] = (uint32_t)(mb >> 32);
            }
        }
    }
}

// ============================== fcC ==============================
// binary FC + BN3 + hardtanh + final 516x10 linear. wave = 2 batches.
__global__ __launch_bounds__(256) void fcC(
    const uint32_t* __restrict__ fcin, const uint32_t* __restrict__ wfcb,
    const float* __restrict__ inv3p, const float* __restrict__ sh3p,
    const float* __restrict__ wlt, const float* __restrict__ blast,
    float* __restrict__ out)
{
    __shared__ uint32_t l_in[288];
    const int t = threadIdx.x, wid = t >> 6, lane = t & 63;

    for (int i = t; i < 288; i += 256) l_in[i] = fcin[blockIdx.x * 288 + i];
    __syncthreads();

    const int b0i = blockIdx.x * 8 + wid * 2;
    const uint32_t* in0 = &l_in[wid * 72];

    int pc0[9], pc1[9];
    #pragma unroll
    for (int q = 0; q < 9; q++) { pc0[q] = 0; pc1[q] = 0; }

    for (int w = 0; w < 36; w++) {
        uint32_t i0 = in0[w], i1 = in0[36 + w];
        const uint32_t* wf = wfcb + w * 576 + lane;
        #pragma unroll
        for (int q = 0; q < 9; q++) {
            uint32_t f = wf[q * 64];
            pc0[q] += __popc(i0 ^ f);
            pc1[q] += __popc(i1 ^ f);
        }
    }

    float oa[2][10];
    #pragma unroll
    for (int b = 0; b < 2; b++)
        #pragma unroll
        for (int k = 0; k < 10; k++) oa[b][k] = 0.f;

    #pragma unroll
    for (int q = 0; q < 9; q++) {
        int j = lane + 64 * q;
        float ivv = inv3p[j], shv = sh3p[j];
        float t0 = fminf(1.f, fmaxf(-1.f, __fadd_rn(__fmul_rn((float)(1152 - 2 * pc0[q]), ivv), shv)));
        float t1 = fminf(1.f, fmaxf(-1.f, __fadd_rn(__fmul_rn((float)(1152 - 2 * pc1[q]), ivv), shv)));
        #pragma unroll
        for (int k = 0; k < 10; k++) {
            float wv = wlt[k * 576 + j];
            oa[0][k] = fmaf(t0, wv, oa[0][k]);
            oa[1][k] = fmaf(t1, wv, oa[1][k]);
        }
    }

    #pragma unroll
    for (int m = 1; m < 64; m <<= 1)
        #pragma unroll
        for (int b = 0; b < 2; b++)
            #pragma unroll
            for (int k = 0; k < 10; k++)
                oa[b][k] += __shfl_xor(oa[b][k], m, 64);

    if (lane == 0) {
        for (int b = 0; b < 2; b++)
            for (int k = 0; k < 10; k++)
                out[(b0i + b) * 10 + k] = oa[b][k] + blast[k];
    }
}

// ============================== launch ==============================
extern "C" void kernel_launch(void* const* d_in, const int* in_sizes, int n_in,
                              void* d_out, int out_size, void* d_ws, size_t ws_size,
                              hipStream_t stream)
{
    (void)in_sizes; (void)n_in; (void)out_size; (void)ws_size;
    const float* x     = (const float*)d_in[0];
    const float* w0    = (const float*)d_in[1];
    const float* b0    = (const float*)d_in[2];
    const float* g1    = (const float*)d_in[3];
    const float* be1   = (const float*)d_in[4];
    const float* m1    = (const float*)d_in[5];
    const float* v1    = (const float*)d_in[6];
    const float* w2    = (const float*)d_in[7];
    const float* g2    = (const float*)d_in[8];
    const float* be2   = (const float*)d_in[9];
    const float* m2    = (const float*)d_in[10];
    const float* v2    = (const float*)d_in[11];
    const float* wfc   = (const float*)d_in[12];
    const float* g3    = (const float*)d_in[13];
    const float* be3   = (const float*)d_in[14];
    const float* m3    = (const float*)d_in[15];
    const float* v3    = (const float*)d_in[16];
    const float* wlast = (const float*)d_in[17];
    const float* blast = (const float*)d_in[18];

    char* ws = (char*)d_ws;
    uint32_t* fcin   = (uint32_t*)(ws + 6422528);       // 8192*36*4  = 1,179,648 B
    uint32_t* w2bits = (uint32_t*)(ws + 7602176);       // 288*4
    uint32_t* wfcb   = (uint32_t*)(ws + 7603328);       // 36*576*4 = 82,944 B
    float*    inv3p  = (float*)(ws + 7686272);          // 576*4
    float*    sh3p   = (float*)(ws + 7688576);          // 576*4
    float*    wlt    = (float*)(ws + 7690880);          // 10*576*4 = 23,040 B
    uint32_t* bfrag  = (uint32_t*)(ws + 7713920);       // 768*16 = 12,288 B (16B aligned)
    float2*   bn1c   = (float2*)(ws + 7726208);         // 32*8 = 256 B

    prep_kernel<<<110, 256, 0, stream>>>(w2, wfc, g3, be3, m3, v3, wlast,
                                         w0, b0, g1, be1, m1, v1,
                                         w2bits, wfcb, inv3p, sh3p, wlt,
                                         bfrag, bn1c);
    convAB<<<8192, 128, 0, stream>>>(x, w0, bfrag, bn1c,
                                     w2bits, g2, be2, m2, v2, fcin);
    fcC<<<1024, 256, 0, stream>>>(fcin, wfcb, inv3p, sh3p, wlt, blast, (float*)d_out);
}